// Round 4
// baseline (238.663 us; speedup 1.0000x reference)
//
#include <hip/hip_runtime.h>

// GINDecor on MI355X (f32). Gate depends only on (deg_row, deg_col) integers
// => 128x128 LUT. Linear tail collapses: M = W1@W2 (256x2), cz = b1@W2,
//   y = x@M,  z = An@y + r*y + cz,  out = An@z + r*z + b2.
// Round 3: k_gatey was latency-bound (VGPR=12 -> serial loads). Now one row
// per WAVE with 16 float4 loads in flight, ballot compaction, no barriers.

typedef unsigned char u8;

#define N_NODES 4096
#define MAX_DEG 128   // mean deg ~41, sd ~6.4
#define LUTD    128

// ---- prep: gate LUT, M = W1@W2, cz = b1@W2, cfin = b2, dc_u8, zero cs ----
__global__ __launch_bounds__(256)
void k_prep(const float* __restrict__ We1, const float* __restrict__ be1,
            const float* __restrict__ We2, const float* __restrict__ be2,
            const float* __restrict__ W1,  const float* __restrict__ b1,
            const float* __restrict__ W2,  const float* __restrict__ b2,
            const float* __restrict__ ydeg,
            float* __restrict__ lut, float* __restrict__ M,
            float* __restrict__ cz, float* __restrict__ cfin,
            u8* __restrict__ dc_u8, float* __restrict__ cs) {
    int b = blockIdx.x, tid = threadIdx.x;
    if (b < 64) {                          // gate LUT over (deg_row, deg_col)
        int e = b * 256 + tid;             // 0..16383
        float dr = (float)(e >> 7), dc = (float)(e & 127);
        float delta = be2[1] - be2[0];
        #pragma unroll
        for (int w = 0; w < 16; ++w) {
            float hh = fmaf(We1[32 + w], dc,
                       fmaf(We1[16 + w], dr, We1[w] + be1[w]));
            hh = fmaxf(hh, 0.f);
            delta = fmaf(hh, We2[w * 2 + 1] - We2[w * 2], delta);
        }
        lut[e] = 1.f / (1.f + __expf(-delta));   // softmax[...,1]
    } else if (b < 66) {                   // M[t*2+d] = sum_h W1[t,h]*W2[h,d]
        int e = (b - 64) * 256 + tid;      // 0..511
        int t = e >> 1, d = e & 1;
        float s = 0.f;
        for (int h = 0; h < 128; ++h)
            s = fmaf(W1[t * 128 + h], W2[h * 2 + d], s);
        M[e] = s;
    } else if (b == 66) {
        if (tid < 2) {
            float s = 0.f;
            for (int h = 0; h < 128; ++h)
                s = fmaf(b1[h], W2[h * 2 + tid], s);
            cz[tid]   = s;
            cfin[tid] = b2[tid];
        }
    } else {                               // dc_u8 table + zero cs
        int j = (b - 67) * 256 + tid;      // 0..4095
        int d = (int)ydeg[j];              // row 0 of ydeg = deg_col broadcast
        dc_u8[j] = (u8)(d > 127 ? 127 : d);
        cs[j] = 0.f;
    }
}

// ---- gate scan: ONE ROW PER WAVE, 16 float4 loads in flight, ballot compact ----
__global__ __launch_bounds__(256)
void k_gatey(const float* __restrict__ adj, const float* __restrict__ xdeg,
             const float* __restrict__ x, const float* __restrict__ lut,
             const u8* __restrict__ dc_u8, const float* __restrict__ M,
             int2* __restrict__ e_g, float* __restrict__ rs,
             float* __restrict__ cs, int* __restrict__ cnt,
             float* __restrict__ y) {
    __shared__ float g_row[4][LUTD];
    const int wv = threadIdx.x >> 6, lane = threadIdx.x & 63;
    const int i = blockIdx.x * 4 + wv;

    // stage this row's LUT slice into per-wave LDS (wave-synchronous, no barrier)
    int dri = (int)xdeg[(size_t)i * N_NODES];       // deg_row[i] (broadcast col 0)
    if (dri > 127) dri = 127;
    float2 g2 = ((const float2*)(lut + dri * LUTD))[lane];
    g_row[wv][lane * 2 + 0] = g2.x;
    g_row[wv][lane * 2 + 1] = g2.y;

    // y = x@M contribution: 4 consecutive features per lane
    float4 xv = ((const float4*)(x + (size_t)i * 256))[lane];
    float4 m01 = ((const float4*)M)[lane * 2 + 0];  // (M[t][0],M[t][1],M[t+1][0],M[t+1][1])
    float4 m23 = ((const float4*)M)[lane * 2 + 1];
    float p0 = xv.x * m01.x + xv.y * m01.z + xv.z * m23.x + xv.w * m23.z;
    float p1 = xv.x * m01.y + xv.y * m01.w + xv.z * m23.y + xv.w * m23.w;

    // adjacency row: 16 independent float4 loads per lane, all issued up front
    const float4* arow4 = (const float4*)(adj + (size_t)i * N_NODES);
    float4 v[16];
    #pragma unroll
    for (int c = 0; c < 16; ++c) v[c] = arow4[lane + 64 * c];

    int2* er = e_g + (size_t)i * MAX_DEG;
    int base = 0;
    float lrs = 0.f;
    const unsigned long long lt_mask = (1ull << lane) - 1ull;
    #pragma unroll
    for (int c = 0; c < 16; ++c) {
        float vals[4] = {v[c].x, v[c].y, v[c].z, v[c].w};
        #pragma unroll
        for (int q = 0; q < 4; ++q) {
            bool nz = (vals[q] != 0.f);
            unsigned long long mask = __ballot(nz);
            if (nz) {
                int j = c * 256 + lane * 4 + q;
                float gate = g_row[wv][dc_u8[j]];
                lrs += gate;
                atomicAdd(cs + j, gate);
                int pos = base + __popcll(mask & lt_mask);
                if (pos < MAX_DEG) er[pos] = make_int2(j, __float_as_int(gate));
            }
            base += __popcll(mask);
        }
    }
    #pragma unroll
    for (int o = 32; o > 0; o >>= 1) {
        lrs += __shfl_down(lrs, o);
        p0  += __shfl_down(p0, o);
        p1  += __shfl_down(p1, o);
    }
    if (lane == 0) {
        rs[i]  = 1.f + lrs;                // + self loop
        cnt[i] = (base < MAX_DEG) ? base : MAX_DEG;
        ((float2*)y)[i] = make_float2(p0, p1);
    }
}

// ---- 2-col SpMV, one row per HALF-wave:
//      vout = drow.*(Agate@(dcol.*vin) + dcol_i*vin_i) + r*vin + add ----
__global__ __launch_bounds__(256)
void k_spmv(const int2* __restrict__ e_g, const int* __restrict__ cnt,
            const float* __restrict__ rs, const float* __restrict__ cs,
            const float* __restrict__ vin, const float* __restrict__ addv,
            const float* __restrict__ rw, float* __restrict__ vout) {
    int sub = threadIdx.x >> 5, lane32 = threadIdx.x & 31;
    int i = blockIdx.x * 8 + sub;
    int nnz = cnt[i];
    const int2* ep = e_g + (size_t)i * MAX_DEG;
    float a0 = 0.f, a1 = 0.f;
    for (int k = lane32; k < nnz; k += 32) {
        int2 e = ep[k];
        float2 vj = ((const float2*)vin)[e.x];
        float wt = __int_as_float(e.y) * rsqrtf(cs[e.x] + 1.f);
        a0 = fmaf(wt, vj.x, a0);
        a1 = fmaf(wt, vj.y, a1);
    }
    #pragma unroll
    for (int o = 16; o > 0; o >>= 1) {
        a0 += __shfl_down(a0, o, 32);
        a1 += __shfl_down(a1, o, 32);
    }
    if (lane32 == 0) {
        float r  = rw[0];
        float di = rsqrtf(rs[i]), ci = rsqrtf(cs[i] + 1.f);
        float2 yv = ((const float2*)vin)[i];
        float2 o;
        o.x = di * (a0 + ci * yv.x) + r * yv.x + addv[0];
        o.y = di * (a1 + ci * yv.y) + r * yv.y + addv[1];
        ((float2*)vout)[i] = o;
    }
}

extern "C" void kernel_launch(void* const* d_in, const int* in_sizes, int n_in,
                              void* d_out, int out_size, void* d_ws, size_t ws_size,
                              hipStream_t stream) {
    const float* x    = (const float*)d_in[0];
    const float* adj  = (const float*)d_in[1];
    const float* xdeg = (const float*)d_in[2];
    const float* ydeg = (const float*)d_in[3];
    const float* We1  = (const float*)d_in[4];
    const float* be1  = (const float*)d_in[5];
    const float* We2  = (const float*)d_in[6];
    const float* be2  = (const float*)d_in[7];
    const float* W1   = (const float*)d_in[8];
    const float* b1   = (const float*)d_in[9];
    const float* W2   = (const float*)d_in[10];
    const float* b2   = (const float*)d_in[11];
    const float* rw   = (const float*)d_in[12];

    char* ws = (char*)d_ws;
    int2*  e_g  = (int2*) (ws + 0);          // 4096*128*8 = 4 MB
    float* lut  = (float*)(ws + 4194304);    // 64 KB
    float* rs   = (float*)(ws + 4259840);    // 16 KB
    float* cs   = (float*)(ws + 4276224);    // 16 KB
    int*   cnt  = (int*)  (ws + 4292608);    // 16 KB
    float* y    = (float*)(ws + 4308992);    // 32 KB
    float* z    = (float*)(ws + 4341760);    // 32 KB
    float* M    = (float*)(ws + 4374528);    // 2 KB
    float* cz   = (float*)(ws + 4376576);    // 8 B
    float* cfin = (float*)(ws + 4376584);    // 8 B
    u8*    dcu  = (u8*)   (ws + 4376592);    // 4 KB

    k_prep<<<83, 256, 0, stream>>>(We1, be1, We2, be2, W1, b1, W2, b2, ydeg,
                                   lut, M, cz, cfin, dcu, cs);
    k_gatey<<<N_NODES / 4, 256, 0, stream>>>(adj, xdeg, x, lut, dcu, M,
                                             e_g, rs, cs, cnt, y);
    k_spmv<<<N_NODES / 8, 256, 0, stream>>>(e_g, cnt, rs, cs, y, cz, rw, z);
    k_spmv<<<N_NODES / 8, 256, 0, stream>>>(e_g, cnt, rs, cs, z, cfin, rw, (float*)d_out);
}

// Round 5
// 197.872 us; speedup vs baseline: 1.2061x; 1.2061x over previous
//
#include <hip/hip_runtime.h>

// GINDecor on MI355X (f32). gate(i,j) = f(deg_row[i], deg_col[j]) -> 128x128 LUT.
// Linear tail collapses: M = W1@W2 (256x2), cz = b1@W2,
//   y = x@M,  z = An@y + r*y + cz,  out = An@z + r*z + b2.
// R4 lesson: per-element ballots/LDS-atomics serialize; wave-per-row starves
// latency hiding. R5: block=row, straight-line loads, per-thread bitmask
// compaction, one LDS atomic per thread-with-edges, direct L1 LUT reads.

typedef unsigned char u8;
typedef unsigned int  u32;

#define N_NODES 4096
#define MAX_DEG 128   // mean deg ~41, sd ~6.4
#define LUTD    128

// ---- prep: gate LUT, M=W1@W2, cz=b1@W2, cfin=b2, dc_u8, dr_u8, zero cs ----
__global__ __launch_bounds__(256)
void k_prep(const float* __restrict__ We1, const float* __restrict__ be1,
            const float* __restrict__ We2, const float* __restrict__ be2,
            const float* __restrict__ W1,  const float* __restrict__ b1,
            const float* __restrict__ W2,  const float* __restrict__ b2,
            const float* __restrict__ xdeg, const float* __restrict__ ydeg,
            float* __restrict__ lut, float* __restrict__ M,
            float* __restrict__ cz, float* __restrict__ cfin,
            u8* __restrict__ dc_u8, u8* __restrict__ dr_u8,
            float* __restrict__ cs) {
    int b = blockIdx.x, tid = threadIdx.x;
    if (b < 64) {                          // gate LUT over (deg_row, deg_col)
        int e = b * 256 + tid;             // 0..16383
        float dr = (float)(e >> 7), dc = (float)(e & 127);
        float delta = be2[1] - be2[0];
        #pragma unroll
        for (int w = 0; w < 16; ++w) {
            float hh = fmaf(We1[32 + w], dc,
                       fmaf(We1[16 + w], dr, We1[w] + be1[w]));
            hh = fmaxf(hh, 0.f);
            delta = fmaf(hh, We2[w * 2 + 1] - We2[w * 2], delta);
        }
        lut[e] = 1.f / (1.f + __expf(-delta));   // softmax[...,1]
    } else if (b < 66) {                   // M[t*2+d] = sum_h W1[t,h]*W2[h,d]
        int e = (b - 64) * 256 + tid;      // 0..511
        int t = e >> 1, d = e & 1;
        float s = 0.f;
        for (int h = 0; h < 128; ++h)
            s = fmaf(W1[t * 128 + h], W2[h * 2 + d], s);
        M[e] = s;
    } else if (b == 66) {
        if (tid < 2) {
            float s = 0.f;
            for (int h = 0; h < 128; ++h)
                s = fmaf(b1[h], W2[h * 2 + tid], s);
            cz[tid]   = s;
            cfin[tid] = b2[tid];
        }
    } else if (b < 83) {                   // dc_u8 (ydeg row 0) + zero cs
        int j = (b - 67) * 256 + tid;      // 0..4095
        int d = (int)ydeg[j];
        dc_u8[j] = (u8)(d > 127 ? 127 : d);
        cs[j] = 0.f;
    } else {                               // dr_u8 (xdeg col 0, stride N)
        int i = (b - 83) * 256 + tid;      // 0..4095
        int d = (int)xdeg[(size_t)i * N_NODES];
        dr_u8[i] = (u8)(d > 127 ? 127 : d);
    }
}

// ---- gate scan: block=row; straight-line loads; bitmask compaction ----
__global__ __launch_bounds__(256)
void k_gatey(const float* __restrict__ adj, const u8* __restrict__ dr_u8,
             const float* __restrict__ x, const float* __restrict__ lut,
             const u8* __restrict__ dc_u8, const float* __restrict__ M,
             int2* __restrict__ e_g, float* __restrict__ rs,
             float* __restrict__ cs, int* __restrict__ cnt,
             float* __restrict__ y) {
    __shared__ int   s_cnt;
    __shared__ float s_rs[4];
    const int i = blockIdx.x, tid = threadIdx.x;
    const int wv = tid >> 6, lane = tid & 63;
    if (tid == 0) s_cnt = 0;

    // --- all global loads issued straight-line, before any consumption ---
    const float4* arow4 = (const float4*)(adj + (size_t)i * N_NODES);
    float4 v0 = arow4[tid * 4 + 0];
    float4 v1 = arow4[tid * 4 + 1];
    float4 v2 = arow4[tid * 4 + 2];
    float4 v3 = arow4[tid * 4 + 3];
    uint4  dcw = ((const uint4*)dc_u8)[tid];      // 16 degree bytes for j=tid*16..+15
    const float* lut_row = lut + (int)dr_u8[i] * LUTD;

    // y = x@M: wave 0 only (64 lanes x float4 = full 256-dim row)
    float p0 = 0.f, p1 = 0.f;
    if (wv == 0) {
        float4 xv  = ((const float4*)(x + (size_t)i * 256))[lane];
        float4 m01 = ((const float4*)M)[lane * 2 + 0];
        float4 m23 = ((const float4*)M)[lane * 2 + 1];
        p0 = xv.x * m01.x + xv.y * m01.z + xv.z * m23.x + xv.w * m23.z;
        p1 = xv.x * m01.y + xv.y * m01.w + xv.z * m23.y + xv.w * m23.w;
    }

    // --- build 16-bit nonzero mask in registers ---
    float vals[16] = {v0.x, v0.y, v0.z, v0.w, v1.x, v1.y, v1.z, v1.w,
                      v2.x, v2.y, v2.z, v2.w, v3.x, v3.y, v3.z, v3.w};
    u32 mask = 0;
    #pragma unroll
    for (int q = 0; q < 16; ++q)
        mask |= (vals[q] != 0.f) ? (1u << q) : 0u;

    float lrs = 0.f;
    int nloc = __popc(mask);
    if (nloc) {                            // ~15% of threads
        int pos = atomicAdd(&s_cnt, nloc); // one LDS atomic per such thread
        int2* er = e_g + (size_t)i * MAX_DEG;
        const u32 w[4] = {dcw.x, dcw.y, dcw.z, dcw.w};
        u32 m = mask;
        while (m) {
            int q = __ffs(m) - 1;
            m &= m - 1;
            int j = tid * 16 + q;
            float gate = lut_row[(w[q >> 2] >> ((q & 3) * 8)) & 255u];
            lrs += gate;
            atomicAdd(cs + j, gate);
            if (pos < MAX_DEG) er[pos] = make_int2(j, __float_as_int(gate));
            ++pos;
        }
    }

    // --- reductions: rs across block, y within wave 0 ---
    #pragma unroll
    for (int o = 32; o > 0; o >>= 1) {
        lrs += __shfl_down(lrs, o);
        p0  += __shfl_down(p0, o);
        p1  += __shfl_down(p1, o);
    }
    if (lane == 0) s_rs[wv] = lrs;
    if (tid == 0)  ((float2*)y)[i] = make_float2(p0, p1);
    __syncthreads();
    if (tid == 0) {
        rs[i]  = 1.f + s_rs[0] + s_rs[1] + s_rs[2] + s_rs[3];  // + self loop
        cnt[i] = (s_cnt < MAX_DEG) ? s_cnt : MAX_DEG;
    }
}

// ---- 2-col SpMV, one row per half-wave:
//      vout = drow.*(Agate@(dcol.*vin) + dcol_i*vin_i) + r*vin + add ----
__global__ __launch_bounds__(256)
void k_spmv(const int2* __restrict__ e_g, const int* __restrict__ cnt,
            const float* __restrict__ rs, const float* __restrict__ cs,
            const float* __restrict__ vin, const float* __restrict__ addv,
            const float* __restrict__ rw, float* __restrict__ vout) {
    int sub = threadIdx.x >> 5, lane32 = threadIdx.x & 31;
    int i = blockIdx.x * 8 + sub;
    int nnz = cnt[i];
    const int2* ep = e_g + (size_t)i * MAX_DEG;
    float a0 = 0.f, a1 = 0.f;
    for (int k = lane32; k < nnz; k += 32) {
        int2 e = ep[k];
        float2 vj = ((const float2*)vin)[e.x];
        float wt = __int_as_float(e.y) * rsqrtf(cs[e.x] + 1.f);
        a0 = fmaf(wt, vj.x, a0);
        a1 = fmaf(wt, vj.y, a1);
    }
    #pragma unroll
    for (int o = 16; o > 0; o >>= 1) {
        a0 += __shfl_down(a0, o, 32);
        a1 += __shfl_down(a1, o, 32);
    }
    if (lane32 == 0) {
        float r  = rw[0];
        float di = rsqrtf(rs[i]), ci = rsqrtf(cs[i] + 1.f);
        float2 yv = ((const float2*)vin)[i];
        float2 o;
        o.x = di * (a0 + ci * yv.x) + r * yv.x + addv[0];
        o.y = di * (a1 + ci * yv.y) + r * yv.y + addv[1];
        ((float2*)vout)[i] = o;
    }
}

extern "C" void kernel_launch(void* const* d_in, const int* in_sizes, int n_in,
                              void* d_out, int out_size, void* d_ws, size_t ws_size,
                              hipStream_t stream) {
    const float* x    = (const float*)d_in[0];
    const float* adj  = (const float*)d_in[1];
    const float* xdeg = (const float*)d_in[2];
    const float* ydeg = (const float*)d_in[3];
    const float* We1  = (const float*)d_in[4];
    const float* be1  = (const float*)d_in[5];
    const float* We2  = (const float*)d_in[6];
    const float* be2  = (const float*)d_in[7];
    const float* W1   = (const float*)d_in[8];
    const float* b1   = (const float*)d_in[9];
    const float* W2   = (const float*)d_in[10];
    const float* b2   = (const float*)d_in[11];
    const float* rw   = (const float*)d_in[12];

    char* ws = (char*)d_ws;
    int2*  e_g  = (int2*) (ws + 0);          // 4096*128*8 = 4 MB
    float* lut  = (float*)(ws + 4194304);    // 64 KB
    float* rs   = (float*)(ws + 4259840);    // 16 KB
    float* cs   = (float*)(ws + 4276224);    // 16 KB
    int*   cnt  = (int*)  (ws + 4292608);    // 16 KB
    float* y    = (float*)(ws + 4308992);    // 32 KB
    float* z    = (float*)(ws + 4341760);    // 32 KB
    float* M    = (float*)(ws + 4374528);    // 2 KB
    float* cz   = (float*)(ws + 4376576);    // 8 B
    float* cfin = (float*)(ws + 4376584);    // 8 B
    u8*    dcu  = (u8*)   (ws + 4376592);    // 4 KB
    u8*    dru  = (u8*)   (ws + 4380688);    // 4 KB

    k_prep<<<99, 256, 0, stream>>>(We1, be1, We2, be2, W1, b1, W2, b2, xdeg, ydeg,
                                   lut, M, cz, cfin, dcu, dru, cs);
    k_gatey<<<N_NODES, 256, 0, stream>>>(adj, dru, x, lut, dcu, M,
                                         e_g, rs, cs, cnt, y);
    k_spmv<<<N_NODES / 8, 256, 0, stream>>>(e_g, cnt, rs, cs, y, cz, rw, z);
    k_spmv<<<N_NODES / 8, 256, 0, stream>>>(e_g, cnt, rs, cs, z, cfin, rw, (float*)d_out);
}